// Round 3
// baseline (3262.903 us; speedup 1.0000x reference)
//
#include <hip/hip_runtime.h>
#include <hip/hip_bf16.h>

// Problem constants
#define B_      32
#define C_      3
#define H_      224
#define W_      224
#define P_      16
#define STRIDE_ 4
#define MS      53            // (224-16)/4+1
#define NP      2809          // MS*MS
#define D_      768
#define NK      196
#define NVIT    197
#define TOPK_   100
#define EPS_    1e-5f
#define M_Q     (B_*NP)       // 89888
#define M_K     (B_*NK)       // 6272
#define M_R     (B_*TOPK_)    // 3200

// ---------------------------------------------------------------------------
// Generic 128x128 tile GEMM, K=768, BK=16, 256 threads, 8x8 acc per thread.
// MODE 0: A = implicit im2col of x_img, batches [b0, b0+nb) -> qchunk (local rows)
// MODE 1: A = vit_features[:,1:,:] rows  (k_lin = vit @ Wk + bk)
// MODE 3: A = implicit im2col of x_img rows gathered by topk -> qsel
// MODE 4: A = qsel rows (sequential); out[:,197:,:] = gamma*(A@Wout + bout)
// ---------------------------------------------------------------------------
template<int MODE>
__global__ __launch_bounds__(256)
void gemm128(const float* __restrict__ A,
             const float* __restrict__ Wm,
             const float* __restrict__ bias,
             float* __restrict__ Out,
             const int* __restrict__ gather,
             const float* __restrict__ gammap,
             int Mtotal, int b0)
{
    __shared__ __align__(16) float As[16][132];   // [kk][row], padded stride
    __shared__ __align__(16) float Bs[16][128];   // [kk][n]

    const int t  = threadIdx.x;
    const int bm = blockIdx.x;
    const int n0 = blockIdx.y * 128;
    const int kl = t & 15;        // k-lane for A staging
    const int rl = t >> 4;        // row-lane base for A staging

    // Per-thread staged rows are fixed across k-iters: rows rl + 16*c
    int arow_base[8];
#pragma unroll
    for (int c = 0; c < 8; ++c) {
        int m = bm * 128 + rl + 16 * c;
        if (m >= Mtotal) m = Mtotal - 1;           // clamp: safe reads, masked writes
        if (MODE == 0) {
            int lb = m / NP;  int p = m - lb * NP;
            int b = b0 + lb;
            int i = p / MS;  int j = p - i * MS;
            arow_base[c] = b * (C_ * H_ * W_) + (i * STRIDE_) * W_ + j * STRIDE_;
        } else if (MODE == 1) {
            int b = m / NK;  int r = m - b * NK;
            arow_base[c] = (b * NVIT + 1 + r) * D_;
        } else if (MODE == 3) {
            int b = m / TOPK_;
            int idx = gather[m];                   // 0..NP-1
            int i = idx / MS;  int j = idx - i * MS;
            arow_base[c] = b * (C_ * H_ * W_) + (i * STRIDE_) * W_ + j * STRIDE_;
        } else {                                   // MODE 4
            arow_base[c] = m * D_;
        }
    }

    const int tx = t & 15;   // col group: n = n0 + tx*8
    const int ty = t >> 4;   // row group: rows ty*8 .. +7

    float acc[8][8];
#pragma unroll
    for (int i = 0; i < 8; ++i)
#pragma unroll
        for (int j = 0; j < 8; ++j) acc[i][j] = 0.0f;

    for (int k0 = 0; k0 < D_; k0 += 16) {
        // ---- stage A tile: As[kl][row] ----
        if (MODE == 0 || MODE == 3) {
            int kg = k0 + kl;                 // kg&15 == kl (k0 % 16 == 0)
            int cc = kg >> 8;
            int pp = (kg >> 4) & 15;
            int off = cc * (H_ * W_) + pp * W_ + kl;
#pragma unroll
            for (int c = 0; c < 8; ++c)
                As[kl][rl + 16 * c] = A[arow_base[c] + off];
        } else {
            int off = k0 + kl;
#pragma unroll
            for (int c = 0; c < 8; ++c)
                As[kl][rl + 16 * c] = A[arow_base[c] + off];
        }
        // ---- stage B tile: Bs[kk][n] (2 x float4 per thread) ----
        {
            int s = t;
            *(float4*)&Bs[s >> 5][(s & 31) * 4] =
                *((const float4*)(Wm + (size_t)(k0 + (s >> 5)) * D_ + n0) + (s & 31));
            s = t + 256;
            *(float4*)&Bs[s >> 5][(s & 31) * 4] =
                *((const float4*)(Wm + (size_t)(k0 + (s >> 5)) * D_ + n0) + (s & 31));
        }
        __syncthreads();
        // ---- compute ----
#pragma unroll
        for (int kk = 0; kk < 16; ++kk) {
            float a[8], bf[8];
            *(float4*)&a[0]  = *(const float4*)&As[kk][ty * 8];
            *(float4*)&a[4]  = *(const float4*)&As[kk][ty * 8 + 4];
            *(float4*)&bf[0] = *(const float4*)&Bs[kk][tx * 8];
            *(float4*)&bf[4] = *(const float4*)&Bs[kk][tx * 8 + 4];
#pragma unroll
            for (int i = 0; i < 8; ++i)
#pragma unroll
                for (int j = 0; j < 8; ++j)
                    acc[i][j] = fmaf(a[i], bf[j], acc[i][j]);
        }
        __syncthreads();
    }

    // ---- epilogue ----
    float4 b0v = *(const float4*)&bias[n0 + tx * 8];
    float4 b1v = *(const float4*)&bias[n0 + tx * 8 + 4];
    float g = (MODE == 4) ? gammap[0] : 1.0f;
#pragma unroll
    for (int i = 0; i < 8; ++i) {
        int m = bm * 128 + ty * 8 + i;
        if (m >= Mtotal) continue;
        float* op;
        if (MODE == 4) {
            int b = m / TOPK_;
            int r = m - b * TOPK_;
            op = Out + ((size_t)(b * (NVIT + TOPK_) + NVIT + r)) * D_ + n0 + tx * 8;
        } else {
            op = Out + (size_t)m * D_ + n0 + tx * 8;
        }
        float4 v0, v1;
        v0.x = acc[i][0] + b0v.x; v0.y = acc[i][1] + b0v.y;
        v0.z = acc[i][2] + b0v.z; v0.w = acc[i][3] + b0v.w;
        v1.x = acc[i][4] + b1v.x; v1.y = acc[i][5] + b1v.y;
        v1.z = acc[i][6] + b1v.z; v1.w = acc[i][7] + b1v.w;
        if (MODE == 4) {
            v0.x *= g; v0.y *= g; v0.z *= g; v0.w *= g;
            v1.x *= g; v1.y *= g; v1.z *= g; v1.w *= g;
        }
        *(float4*)op = v0;
        *((float4*)op + 1) = v1;
    }
}

// ---------------------------------------------------------------------------
// LayerNorm row stats (mu, rsqrt(var+eps)) -- 192 threads, one block per row
// ---------------------------------------------------------------------------
__global__ __launch_bounds__(192)
void ln_stats(const float* __restrict__ X, float* __restrict__ muv,
              float* __restrict__ rsv)
{
    int m = blockIdx.x, t = threadIdx.x;
    float4 v = *((const float4*)(X + (size_t)m * D_) + t);
    float s  = v.x + v.y + v.z + v.w;
    float s2 = v.x * v.x + v.y * v.y + v.z * v.z + v.w * v.w;
#pragma unroll
    for (int o = 1; o < 64; o <<= 1) { s += __shfl_xor(s, o); s2 += __shfl_xor(s2, o); }
    __shared__ float red[6];
    if ((t & 63) == 0) { red[t >> 6] = s; red[3 + (t >> 6)] = s2; }
    __syncthreads();
    if (t == 0) {
        float S = red[0] + red[1] + red[2];
        float S2 = red[3] + red[4] + red[5];
        float mu = S * (1.0f / D_);
        float var = S2 * (1.0f / D_) - mu * mu;
        muv[m] = mu;
        rsv[m] = rsqrtf(var + EPS_);
    }
}

// ---------------------------------------------------------------------------
// In-place LayerNorm apply -- 192 threads, one block per row
// ---------------------------------------------------------------------------
__global__ __launch_bounds__(192)
void ln_apply(float* __restrict__ X, const float* __restrict__ w,
              const float* __restrict__ bb)
{
    int m = blockIdx.x, t = threadIdx.x;
    float4* rowp = (float4*)(X + (size_t)m * D_);
    float4 v = rowp[t];
    float s  = v.x + v.y + v.z + v.w;
    float s2 = v.x * v.x + v.y * v.y + v.z * v.z + v.w * v.w;
#pragma unroll
    for (int o = 1; o < 64; o <<= 1) { s += __shfl_xor(s, o); s2 += __shfl_xor(s2, o); }
    __shared__ float red[6];
    if ((t & 63) == 0) { red[t >> 6] = s; red[3 + (t >> 6)] = s2; }
    __syncthreads();
    float S = red[0] + red[1] + red[2];
    float S2 = red[3] + red[4] + red[5];
    float mu = S * (1.0f / D_);
    float var = S2 * (1.0f / D_) - mu * mu;
    float rs = rsqrtf(var + EPS_);
    float4 w4 = ((const float4*)w)[t];
    float4 b4 = ((const float4*)bb)[t];
    v.x = (v.x - mu) * rs * w4.x + b4.x;
    v.y = (v.y - mu) * rs * w4.y + b4.y;
    v.z = (v.z - mu) * rs * w4.z + b4.z;
    v.w = (v.w - mu) * rs * w4.w + b4.w;
    rowp[t] = v;
}

// ---------------------------------------------------------------------------
// scores = rowmax( LN(q_chunk) @ kn^T )  for batches [b0, b0+gridDim.y).
// Scale 1/sqrt(D) dropped: monotonic, only indices are consumed downstream.
// Tile: 128 q-rows x 64 k-cols, BK=16, 256 thr, 4x8 acc.
// ---------------------------------------------------------------------------
__global__ __launch_bounds__(256)
void energy_rowmax(const float* __restrict__ qlin, const float* __restrict__ qmu,
                   const float* __restrict__ qrs, const float* __restrict__ lnw,
                   const float* __restrict__ lnb, const float* __restrict__ kn,
                   float* __restrict__ scores, int b0)
{
    __shared__ __align__(16) float qs[16][132];
    __shared__ __align__(16) float ks[16][68];

    const int lb = blockIdx.y;          // local batch in chunk
    const int b  = b0 + lb;             // global batch
    const int m0 = blockIdx.x * 128;
    const int t  = threadIdx.x;
    const int dl = t & 15;
    const int rlb = t >> 4;

    // fixed staged rows -> preload bases + LN stats (local chunk rows)
    int  qbase[8];
    float mu8[8], rs8[8];
#pragma unroll
    for (int c = 0; c < 8; ++c) {
        int p = m0 + rlb + 16 * c;
        if (p > NP - 1) p = NP - 1;
        int lrow = lb * NP + p;
        qbase[c] = lrow * D_ + dl;
        mu8[c] = qmu[lrow];
        rs8[c] = qrs[lrow];
    }

    const int rg = t >> 3;   // 0..31 -> rows rg*4..+3
    const int jg = t & 7;    // 0..7  -> cols jg*8..+7
    const float NEG = -__builtin_inff();
    float rm[4] = {NEG, NEG, NEG, NEG};

    for (int j0 = 0; j0 < NK; j0 += 64) {
        float acc[4][8];
#pragma unroll
        for (int i = 0; i < 4; ++i)
#pragma unroll
            for (int j = 0; j < 8; ++j) acc[i][j] = 0.0f;

        for (int d0 = 0; d0 < D_; d0 += 16) {
            float lwv = lnw[d0 + dl];
            float lbv = lnb[d0 + dl];
#pragma unroll
            for (int c = 0; c < 8; ++c) {
                float vv = qlin[qbase[c] + d0];
                qs[dl][rlb + 16 * c] = (vv - mu8[c]) * rs8[c] * lwv + lbv;
            }
#pragma unroll
            for (int c = 0; c < 4; ++c) {
                int jj = rlb + 16 * c;
                int j = j0 + jj;
                ks[dl][jj] = (j < NK) ? kn[(size_t)(b * NK + j) * D_ + d0 + dl] : 0.0f;
            }
            __syncthreads();
#pragma unroll
            for (int kk = 0; kk < 16; ++kk) {
                float a[4], bf[8];
                *(float4*)&a[0]  = *(const float4*)&qs[kk][rg * 4];
                *(float4*)&bf[0] = *(const float4*)&ks[kk][jg * 8];
                *(float4*)&bf[4] = *(const float4*)&ks[kk][jg * 8 + 4];
#pragma unroll
                for (int i = 0; i < 4; ++i)
#pragma unroll
                    for (int j = 0; j < 8; ++j)
                        acc[i][j] = fmaf(a[i], bf[j], acc[i][j]);
            }
            __syncthreads();
        }
#pragma unroll
        for (int j = 0; j < 8; ++j) {
            if (j0 + jg * 8 + j < NK) {
#pragma unroll
                for (int i = 0; i < 4; ++i) rm[i] = fmaxf(rm[i], acc[i][j]);
            }
        }
    }

    // reduce across the 8 jg lanes (contiguous within a wave)
#pragma unroll
    for (int o = 1; o < 8; o <<= 1) {
#pragma unroll
        for (int i = 0; i < 4; ++i) rm[i] = fmaxf(rm[i], __shfl_xor(rm[i], o));
    }
    if ((t & 7) == 0) {
#pragma unroll
        for (int i = 0; i < 4; ++i) {
            int p = m0 + rg * 4 + i;
            if (p < NP) scores[b * NP + p] = rm[i];
        }
    }
}

// ---------------------------------------------------------------------------
// 3x3 local max (pad -inf), keep = (s == localmax), diversified = keep ? s : 0
// ---------------------------------------------------------------------------
__global__ __launch_bounds__(256)
void localmax_kernel(const float* __restrict__ scores, float* __restrict__ divers)
{
    int b = blockIdx.x;
    const float* sb = scores + b * NP;
    for (int p = threadIdx.x; p < NP; p += blockDim.x) {
        int i = p / MS, j = p - i * MS;
        float s = sb[p];
        float m = s;
        for (int di = -1; di <= 1; ++di) {
            int ni = i + di;
            if (ni < 0 || ni >= MS) continue;
            for (int dj = -1; dj <= 1; ++dj) {
                int nj = j + dj;
                if (nj < 0 || nj >= MS) continue;
                m = fmaxf(m, sb[ni * MS + nj]);
            }
        }
        divers[b * NP + p] = (s == m) ? s : 0.0f;
    }
}

// ---------------------------------------------------------------------------
// Top-100 per batch: full bitonic sort of 4096 (pad -inf) in LDS.
// Order: value desc, tie -> smaller index first (lax.top_k semantics).
// ---------------------------------------------------------------------------
__global__ __launch_bounds__(1024)
void topk_kernel(const float* __restrict__ divers, int* __restrict__ topk)
{
    __shared__ float v[4096];
    __shared__ int  id[4096];
    int b = blockIdx.x, t = threadIdx.x;
    for (int s = t; s < 4096; s += 1024) {
        v[s]  = (s < NP) ? divers[b * NP + s] : -__builtin_inff();
        id[s] = s;
    }
    __syncthreads();
    for (int k = 2; k <= 4096; k <<= 1) {
        for (int j = k >> 1; j > 0; j >>= 1) {
            for (int s = t; s < 2048; s += 1024) {
                int i = 2 * (s & ~(j - 1)) + (s & (j - 1));
                int p = i + j;
                bool desc = ((i & k) == 0);
                float a = v[i], c = v[p];
                int ia = id[i], ic = id[p];
                bool a_less = (a < c) || (a == c && ia > ic);
                if (a_less == desc) {
                    v[i] = c;  v[p] = a;
                    id[i] = ic; id[p] = ia;
                }
            }
            __syncthreads();
        }
    }
    if (t < TOPK_) topk[b * TOPK_ + t] = id[t];
}

// ---------------------------------------------------------------------------
// Copy vit_features into out[:, :197, :]
// ---------------------------------------------------------------------------
__global__ __launch_bounds__(192)
void copy_vit(const float* __restrict__ vit, float* __restrict__ out)
{
    int r = blockIdx.x;                 // 0 .. B*197-1
    int b = r / NVIT, rr = r - b * NVIT;
    const float4* src = (const float4*)(vit + (size_t)r * D_);
    float4* dst = (float4*)(out + ((size_t)(b * (NVIT + TOPK_) + rr)) * D_);
    dst[threadIdx.x] = src[threadIdx.x];
}

// ---------------------------------------------------------------------------
extern "C" void kernel_launch(void* const* d_in, const int* in_sizes, int n_in,
                              void* d_out, int out_size, void* d_ws, size_t ws_size,
                              hipStream_t stream)
{
    const float* x_img = (const float*)d_in[0];
    const float* vit   = (const float*)d_in[1];
    const float* Wq    = (const float*)d_in[2];
    const float* bq    = (const float*)d_in[3];
    const float* lnq_w = (const float*)d_in[4];
    const float* lnq_b = (const float*)d_in[5];
    const float* Wk    = (const float*)d_in[6];
    const float* bk    = (const float*)d_in[7];
    const float* lnk_w = (const float*)d_in[8];
    const float* lnk_b = (const float*)d_in[9];
    const float* Wout  = (const float*)d_in[10];
    const float* bout  = (const float*)d_in[11];
    const float* gamma = (const float*)d_in[12];
    float* out = (float*)d_out;

    // ---- workspace layout (fixed part ~30.6 MB; q-chunk buffer gets the rest)
    float* kbuf   = (float*)d_ws;                    // M_K * D          (19.3 MB)
    float* qmu    = kbuf + (size_t)M_K * D_;         // M_Q              (0.36 MB)
    float* qrs    = qmu + M_Q;                       // M_Q
    float* scores = qrs + M_Q;                       // M_Q
    float* divers = scores + M_Q;                    // M_Q
    float* qsel   = divers + M_Q;                    // M_R * D          (9.8 MB)
    int*   topk   = (int*)(qsel + (size_t)M_R * D_); // M_R
    float* qchunk = (float*)(topk + M_R);            // chunk_batches * NP * D

    // adaptive chunking: fit the q_lin working set into whatever ws remains.
    // ws_size is constant across calls -> same work every call (capture-safe).
    size_t fixedBytes = (size_t)((char*)qchunk - (char*)d_ws);
    size_t avail = (ws_size > fixedBytes) ? (ws_size - fixedBytes) : 0;
    size_t perBatch = (size_t)NP * D_ * sizeof(float);   // 8.63 MB
    int chunk_batches = (int)(avail / perBatch);
    if (chunk_batches < 1) chunk_batches = 1;
    if (chunk_batches > B_) chunk_batches = B_;

    // 1. out[:, :197, :] = vit_features
    copy_vit<<<B_ * NVIT, 192, 0, stream>>>(vit, out);

    // 2. k_lin = vit[:,1:,:] @ Wk + bk ; kn = LN(k_lin) in place
    gemm128<1><<<dim3(M_K / 128, 6), 256, 0, stream>>>(
        vit, Wk, bk, kbuf, nullptr, nullptr, M_K, 0);
    ln_apply<<<M_K, 192, 0, stream>>>(kbuf, lnk_w, lnk_b);

    // 3. chunked q pipeline: q_lin chunk -> LN stats -> energy rowmax scores
    for (int done = 0; done < B_; ) {
        int nb = chunk_batches;
        if (nb > B_ - done) nb = B_ - done;
        int rows = nb * NP;
        gemm128<0><<<dim3((rows + 127) / 128, 6), 256, 0, stream>>>(
            x_img, Wq, bq, qchunk, nullptr, nullptr, rows, done);
        ln_stats<<<rows, 192, 0, stream>>>(qchunk, qmu, qrs);
        energy_rowmax<<<dim3((NP + 127) / 128, nb), 256, 0, stream>>>(
            qchunk, qmu, qrs, lnq_w, lnq_b, kbuf, scores, done);
        done += nb;
    }

    // 4. 3x3 local max -> diversified ; top-100 indices per batch
    localmax_kernel<<<B_, 256, 0, stream>>>(scores, divers);
    topk_kernel<<<B_, 1024, 0, stream>>>(divers, topk);

    // 5. recompute selected q_lin rows (gather-im2col), then refined -> out
    gemm128<3><<<dim3(M_R / 128, 6), 256, 0, stream>>>(
        x_img, Wq, bq, qsel, topk, nullptr, M_R, 0);
    gemm128<4><<<dim3(M_R / 128, 6), 256, 0, stream>>>(
        qsel, Wout, bout, out, nullptr, gamma, M_R, 0);
}